// Round 1
// 153.293 us; speedup vs baseline: 1.0149x; 1.0149x over previous
//
#include <hip/hip_runtime.h>
#include <cstdint>
#include <cstddef>

#define BB 8
#define NN 2048
#define DD 256
#define EE 16
#define HH 8
#define CAPC 256
#define BN (BB*NN)   // 16384
#define EB (EE*BB)   // 128

// ================================================================ kernel 1:
// blocks 0..255   : gating (64 tokens each), per-block loss partials (no atomics)
// blocks 256..383 : qr per (e,h): q[b]=audio[b]@Wq[e]; r[b][d]=Wk[e][d,h*32:]·q_head
__global__ __launch_bounds__(256) void fused_gq_kernel(
    const float* __restrict__ x, const float* __restrict__ wg,
    const float* __restrict__ audio, const float* __restrict__ Wq,
    const float* __restrict__ Wkv,
    int* __restrict__ idx1a, int* __restrict__ idx2a,
    float* __restrict__ g1a, float* __restrict__ g2a,
    float* __restrict__ raw_part, float* __restrict__ cnt_part,
    float* __restrict__ rws)
{
  __shared__ union SM {
    struct { float wgS[DD*EE]; float lgp[4][64][17]; } g;                     // 33.4 KB
    struct { float aS[DD][8]; float qpart[8][32][9]; float qS[32][8];
             float wkS[DD][33]; } q;                                          // 52 KB
  } sm;
  int tid = threadIdx.x;

  if (blockIdx.x < 256) {
    // ---------------- gating ----------------
    for (int t = tid; t < DD*EE; t += 256) sm.g.wgS[t] = wg[t];
    __syncthreads();
    int tk = tid & 63, kc = tid >> 6;
    int token0 = blockIdx.x * 64;
    int token = token0 + tk;
    const float4* xr = (const float4*)(x + (size_t)token*DD + kc*64);
    const float4* wg4 = (const float4*)sm.g.wgS;
    float lg[16];
#pragma unroll
    for (int e = 0; e < 16; ++e) lg[e] = 0.f;
#pragma unroll
    for (int d4 = 0; d4 < 16; ++d4) {
      float4 xv = xr[d4];
      float xa[4] = {xv.x, xv.y, xv.z, xv.w};
#pragma unroll
      for (int dd = 0; dd < 4; ++dd) {
        int d = kc*64 + d4*4 + dd;
        float xc = xa[dd];
#pragma unroll
        for (int j = 0; j < 4; ++j) {
          float4 w = wg4[d*4 + j];
          lg[4*j+0] += xc*w.x; lg[4*j+1] += xc*w.y;
          lg[4*j+2] += xc*w.z; lg[4*j+3] += xc*w.w;
        }
      }
    }
#pragma unroll
    for (int e = 0; e < 16; ++e) sm.g.lgp[kc][tk][e] = lg[e];
    __syncthreads();
    if (tid < 64) {
      int lane = tid;
      float l[16];
#pragma unroll
      for (int e = 0; e < 16; ++e)
        l[e] = sm.g.lgp[0][lane][e] + sm.g.lgp[1][lane][e]
             + sm.g.lgp[2][lane][e] + sm.g.lgp[3][lane][e];
      float mx = l[0];
#pragma unroll
      for (int e = 1; e < 16; ++e) mx = fmaxf(mx, l[e]);
      float p[16]; float s = 0.f;
#pragma unroll
      for (int e = 0; e < 16; ++e) { p[e] = expf(l[e] - mx); s += p[e]; }
      int i1 = 0; float b1 = p[0];
#pragma unroll
      for (int e = 1; e < 16; ++e) { if (p[e] > b1) { b1 = p[e]; i1 = e; } }
      float b2 = (i1 == 0) ? 0.f : p[0]; int i2 = 0;
#pragma unroll
      for (int e = 1; e < 16; ++e) { float v = (e == i1) ? 0.f : p[e]; if (v > b2) { b2 = v; i2 = e; } }
      float inv = 1.f / s;
      float g1 = b1*inv, g2 = b2*inv;
      float den = g1 + g2 + 1e-9f;
      g1 /= den; g2 /= den;
      int tok = token0 + lane;
      idx1a[tok] = i1; idx2a[tok] = i2;
      g1a[tok] = g1;   g2a[tok] = g2;
      int blk = blockIdx.x;
#pragma unroll
      for (int e = 0; e < 16; ++e) {
        float v = p[e] * inv;
        v += __shfl_down(v, 32); v += __shfl_down(v, 16);
        v += __shfl_down(v, 8);  v += __shfl_down(v, 4);
        v += __shfl_down(v, 2);  v += __shfl_down(v, 1);
        unsigned long long mb = __ballot(i1 == e);
        if (lane == 0) {
          raw_part[blk*16 + e] = v;
          cnt_part[blk*16 + e] = (float)__popcll(mb);
        }
      }
    }
  } else {
    // ---------------- qr per (e,h) ----------------
    int eh = blockIdx.x - 256;
    int e = eh >> 3, h = eh & 7;
    for (int i = tid; i < 2048; i += 256) { int b = i >> 8, k = i & 255; sm.q.aS[k][b] = audio[b*DD + k]; }
    __syncthreads();
    int j = tid & 31, kg = tid >> 5;
    const float* wq = Wq + (size_t)e*DD*DD + h*32 + j;
    float acc[8] = {0,0,0,0,0,0,0,0};
#pragma unroll
    for (int i = 0; i < 32; ++i) {
      int k = kg*32 + i;
      float w = wq[(size_t)k*DD];
      float4 a0 = *(const float4*)&sm.q.aS[k][0];
      float4 a1 = *(const float4*)&sm.q.aS[k][4];
      acc[0]+=w*a0.x; acc[1]+=w*a0.y; acc[2]+=w*a0.z; acc[3]+=w*a0.w;
      acc[4]+=w*a1.x; acc[5]+=w*a1.y; acc[6]+=w*a1.z; acc[7]+=w*a1.w;
    }
#pragma unroll
    for (int b = 0; b < 8; ++b) sm.q.qpart[kg][j][b] = acc[b];
    const float* wkbase = Wkv + (size_t)e*(DD*2*DD) + h*32;
    float4 stg[8];
#pragma unroll
    for (int m = 0; m < 8; ++m) {
      int row = m*32 + (tid >> 3), c4 = tid & 7;
      stg[m] = *(const float4*)(wkbase + (size_t)row*(2*DD) + c4*4);
    }
#pragma unroll
    for (int m = 0; m < 8; ++m) {
      int row = m*32 + (tid >> 3), c4 = tid & 7;
      sm.q.wkS[row][c4*4+0] = stg[m].x; sm.q.wkS[row][c4*4+1] = stg[m].y;
      sm.q.wkS[row][c4*4+2] = stg[m].z; sm.q.wkS[row][c4*4+3] = stg[m].w;
    }
    __syncthreads();
    {
      int jj = tid >> 3, b = tid & 7;
      float s = 0.f;
#pragma unroll
      for (int g = 0; g < 8; ++g) s += sm.q.qpart[g][jj][b];
      sm.q.qS[jj][b] = s;
    }
    __syncthreads();
    int d = tid;
    float racc[8] = {0,0,0,0,0,0,0,0};
#pragma unroll
    for (int jj = 0; jj < 32; ++jj) {
      float w = sm.q.wkS[d][jj];
      float4 q0 = *(const float4*)&sm.q.qS[jj][0];
      float4 q1 = *(const float4*)&sm.q.qS[jj][4];
      racc[0]+=w*q0.x; racc[1]+=w*q0.y; racc[2]+=w*q0.z; racc[3]+=w*q0.w;
      racc[4]+=w*q1.x; racc[5]+=w*q1.y; racc[6]+=w*q1.z; racc[7]+=w*q1.w;
    }
#pragma unroll
    for (int b = 0; b < 8; ++b)
      rws[((size_t)(e*8 + b))*2048 + d*8 + h] = racc[b];
  }
}

// ================================================================ kernel 2: scan (per batch) + slot init + loss
// blocks 0..7: scan per batch.  blocks 8..63: L3 prefetch of Wkv/Wp (the fills
// between iterations evict L3; the late expert phases would otherwise read
// these cold on the critical path while scan idles 248 CUs).
__global__ __launch_bounds__(256) void scan_kernel(
    const int* __restrict__ idx1a, const int* __restrict__ idx2a,
    float* __restrict__ g1a, float* __restrict__ g2a, int* __restrict__ slot_token,
    const float* __restrict__ raw_part, const float* __restrict__ cnt_part,
    const float* __restrict__ Wkv, const float* __restrict__ Wp,
    float* __restrict__ dummy,
    float* __restrict__ out_loss)
{
  int tid = threadIdx.x;
  if (blockIdx.x >= BB) {
    // ---- prefetch Wkv (524288 f4) + Wp (262144 f4) into L3 ----
    int pid = (blockIdx.x - BB)*256 + tid;
    const float4* wk4 = (const float4*)Wkv;
    const float4* wp4 = (const float4*)Wp;
    float s = 0.f;
    for (int i = pid; i < 786432; i += 56*256) {
      float4 v = (i < 524288) ? wk4[i] : wp4[i - 524288];
      s += v.x + v.y + v.z + v.w;
    }
    if (s != 0.f) dummy[pid & 1023] = s;   // keep loads live
    return;
  }
  __shared__ unsigned long long m1s[16][32], m2s[16][32];
  __shared__ int wp1[16][32], wp2[16][32], mcnt[16];
  int b = blockIdx.x;
  int wave = tid >> 6, lane = tid & 63;
  for (int i = tid; i < 16*CAPC; i += 256) {
    int e = i >> 8, s = i & 255;
    slot_token[(e*BB + b)*CAPC + s] = -1;
  }
  for (int w = wave; w < 32; w += 4) {
    int token = b*NN + w*64 + lane;
    int i1 = idx1a[token], i2 = idx2a[token];
#pragma unroll
    for (int e = 0; e < 16; ++e) {
      unsigned long long ma = __ballot(i1 == e);
      unsigned long long mb = __ballot(i2 == e);
      if (lane == 0) { m1s[e][w] = ma; m2s[e][w] = mb; }
    }
  }
  __syncthreads();
  if (tid < 16) {
    int run = 0;
    for (int w = 0; w < 32; ++w) { wp1[tid][w] = run; run += (int)__popcll(m1s[tid][w]); }
    mcnt[tid] = run < CAPC ? run : CAPC;
  } else if (tid < 32) {
    int e2 = tid - 16; int run = 0;
    for (int w = 0; w < 32; ++w) { wp2[e2][w] = run; run += (int)__popcll(m2s[e2][w]); }
  }
  __syncthreads();
  for (int w = wave; w < 32; w += 4) {
    int token = b*NN + w*64 + lane;
    int i1 = idx1a[token], i2 = idx2a[token];
    unsigned long long lt = (1ull << lane) - 1ull;
    int pos1 = wp1[i1][w] + (int)__popcll(m1s[i1][w] & lt);
    float g1 = g1a[token];
    bool k1 = pos1 < CAPC;
    g1a[token] = k1 ? g1 : 0.f;
    if (k1) slot_token[(i1*BB + b)*CAPC + pos1] = token;
    int pos2 = mcnt[i2] + wp2[i2][w] + (int)__popcll(m2s[i2][w] & lt);
    float g2 = g2a[token];
    bool k2 = pos2 < CAPC;
    g2a[token] = k2 ? g2 : 0.f;
    if (k2 && g2 > 0.f) slot_token[(i2*BB + b)*CAPC + pos2] = token;
  }
  if (blockIdx.x == 0) {
    float v = 0.f;
    if (tid < 128) {
      int bb = tid >> 4, e = tid & 15;
      float rs = 0.f, cs = 0.f;
#pragma unroll 4
      for (int k = 0; k < 32; ++k) {
        rs += raw_part[(bb*32 + k)*16 + e];
        cs += cnt_part[(bb*32 + k)*16 + e];
      }
      v = (rs * (1.f/(float)NN)) * (cs * (1.f/(float)NN));
    }
    v += __shfl_down(v, 32); v += __shfl_down(v, 16); v += __shfl_down(v, 8);
    v += __shfl_down(v, 4);  v += __shfl_down(v, 2);  v += __shfl_down(v, 1);
    __shared__ float r4[4];
    if ((tid & 63) == 0) r4[tid >> 6] = v;
    __syncthreads();
    if (tid == 0)
      out_loss[0] = (r4[0]+r4[1]+r4[2]+r4[3]) * ((float)(EE*EE) / (float)(BB*EE)) * 0.01f;
  }
}

// ================================================================ kernel 3 (fused):
// per (e,b) block: slot logits -> softmax -> attn gather -> @Wv -> @Wp + sigmoid
// grid = EB (128) blocks x 512 threads. All intermediates stay in LDS.
__global__ __launch_bounds__(512) void expert_kernel(
    const float* __restrict__ x, const float* __restrict__ rws,
    const int* __restrict__ slot_token, const float* __restrict__ Wkv,
    const float* __restrict__ Wp, const float* __restrict__ bp,
    float* __restrict__ gateW)
{
  __shared__ float rS[DD][8];        // 8 KB   r[d][h]
  __shared__ int   tokS[CAPC];       // 1 KB
  __shared__ float lp[2][CAPC][9];   // 18.4 KB logit partials
  __shared__ float aST[CAPC][8];     // 8 KB   logits, then probs [s][h]
  __shared__ float part[2][8][DD];   // 16 KB  gather partials
  __shared__ float xaS[8][DD];       // 8 KB   attn-weighted x [h][d]
  __shared__ float oS[DD];           // 1 KB   o for this (e,b)
  __shared__ float op[2][DD];        // 2 KB   GEMV partials
  int tid = threadIdx.x;
  int eb = blockIdx.x;
  int e  = eb >> 3;

  {
    const float4* rin = (const float4*)(rws + (size_t)eb*2048);
    ((float4*)rS)[tid] = rin[tid];                // 512 f4 = 8 KB
    if (tid < CAPC) tokS[tid] = slot_token[eb*CAPC + tid];
  }
  __syncthreads();

  // ---- phase A: logits  l[s][h] = sum_d x[tok_s][d] * r[d][h] ----
  {
    int s = tid >> 1, q = tid & 1;     // 2 threads per slot, interleaved f4
    int token = tokS[s];
    float l[8] = {0,0,0,0,0,0,0,0};
    if (token >= 0) {
      const float4* xr = (const float4*)(x + (size_t)token*DD) + q;
#pragma unroll
      for (int i = 0; i < 32; ++i) {
        float4 xv = xr[i*2];
        float xa[4] = {xv.x, xv.y, xv.z, xv.w};
#pragma unroll
        for (int dd = 0; dd < 4; ++dd) {
          int d = i*8 + q*4 + dd;
          float4 r0 = *(const float4*)&rS[d][0];
          float4 r1 = *(const float4*)&rS[d][4];
          float xc = xa[dd];
          l[0]+=xc*r0.x; l[1]+=xc*r0.y; l[2]+=xc*r0.z; l[3]+=xc*r0.w;
          l[4]+=xc*r1.x; l[5]+=xc*r1.y; l[6]+=xc*r1.z; l[7]+=xc*r1.w;
        }
      }
    }
#pragma unroll
    for (int h = 0; h < 8; ++h) lp[q][s][h] = l[h];
  }
  __syncthreads();
#pragma unroll
  for (int r = 0; r < 4; ++r) {
    int idx = r*512 + tid;             // 0..2047
    int s2 = idx >> 3, h2 = idx & 7;
    aST[s2][h2] = (lp[0][s2][h2] + lp[1][s2][h2]) * 0.17677669529663687f; // 32^-0.5
  }
  __syncthreads();

  // ---- phase B: softmax over 256 slots per head (wave w owns head h=w) ----
  {
    int wave = tid >> 6, lane = tid & 63;
    int h = wave;
    float v0 = aST[lane][h],     v1 = aST[lane+64][h];
    float v2 = aST[lane+128][h], v3 = aST[lane+192][h];
    float m = fmaxf(fmaxf(v0, v1), fmaxf(v2, v3));
    m = fmaxf(m, __shfl_down(m, 32)); m = fmaxf(m, __shfl_down(m, 16));
    m = fmaxf(m, __shfl_down(m, 8));  m = fmaxf(m, __shfl_down(m, 4));
    m = fmaxf(m, __shfl_down(m, 2));  m = fmaxf(m, __shfl_down(m, 1));
    m = __shfl(m, 0);
    float e0 = expf(v0 - m), e1 = expf(v1 - m), e2 = expf(v2 - m), e3 = expf(v3 - m);
    float sm = e0 + e1 + e2 + e3;
    sm += __shfl_down(sm, 32); sm += __shfl_down(sm, 16); sm += __shfl_down(sm, 8);
    sm += __shfl_down(sm, 4);  sm += __shfl_down(sm, 2);  sm += __shfl_down(sm, 1);
    sm = __shfl(sm, 0);
    float inv = 1.f / sm;
    aST[lane][h]     = e0*inv; aST[lane+64][h]  = e1*inv;
    aST[lane+128][h] = e2*inv; aST[lane+192][h] = e3*inv;
  }
  __syncthreads();

  // ---- phase C: gather  xa[h][d] = sum_s a[s][h] * x[tok_s][d] ----
  {
    int d = tid & 255, sc = tid >> 8;  // sc in {0,1}: 128 slots each
    const float* xb = x + d;
    float acc[8] = {0,0,0,0,0,0,0,0};
#pragma unroll 4
    for (int i = 0; i < 128; ++i) {
      int s2 = sc*128 + i;
      int tk = tokS[s2];
      int tkc = tk < 0 ? 0 : tk;
      float msk = tk < 0 ? 0.f : 1.f;
      float xv = xb[(size_t)tkc*DD] * msk;
      float4 a0 = *(const float4*)&aST[s2][0];
      float4 a1 = *(const float4*)&aST[s2][4];
      acc[0]+=a0.x*xv; acc[1]+=a0.y*xv; acc[2]+=a0.z*xv; acc[3]+=a0.w*xv;
      acc[4]+=a1.x*xv; acc[5]+=a1.y*xv; acc[6]+=a1.z*xv; acc[7]+=a1.w*xv;
    }
#pragma unroll
    for (int h = 0; h < 8; ++h) part[sc][h][d] = acc[h];
  }
  __syncthreads();
#pragma unroll
  for (int r = 0; r < 4; ++r) {
    int idx = r*512 + tid;
    int h2 = idx >> 8, d2 = idx & 255;
    xaS[h2][d2] = part[0][h2][d2] + part[1][h2][d2];
  }
  __syncthreads();

  // ---- phase D: o[c] = sum_d xa[h(c)][d] * Wv[d][c],  h(c)=c>>5 ----
  {
    int c = tid & 255, kc = tid >> 8;
    int h = c >> 5;
    const float* wv = Wkv + (size_t)e*(DD*2*DD) + DD + c;
    float a = 0.f;
#pragma unroll 8
    for (int i = 0; i < 128; ++i) {
      int d2 = kc*128 + i;
      a += wv[(size_t)d2*(2*DD)] * xaS[h][d2];
    }
    op[kc][c] = a;
  }
  __syncthreads();
  if (tid < DD) oS[tid] = op[0][tid] + op[1][tid];
  __syncthreads();

  // ---- phase E: gate[c] = sigmoid(bp[c] + sum_d o[d] * Wp[d][c]) ----
  {
    int c = tid & 255, kc = tid >> 8;
    const float* wp = Wp + (size_t)e*DD*DD + c;
    float a = 0.f;
#pragma unroll 8
    for (int i = 0; i < 128; ++i) {
      int d2 = kc*128 + i;
      a += wp[(size_t)d2*DD] * oS[d2];
    }
    op[kc][c] = a;
  }
  __syncthreads();
  if (tid < DD) {
    float sv = bp[e*DD + tid] + op[0][tid] + op[1][tid];
    gateW[(size_t)eb*DD + tid] = 1.f / (1.f + expf(-sv));
  }
}

// ================================================================ kernel 4: recombine (float4)
__global__ __launch_bounds__(256) void out_kernel(
    const float* __restrict__ x, const float* __restrict__ g1f, const float* __restrict__ g2f,
    const int* __restrict__ idx1a, const int* __restrict__ idx2a,
    const float* __restrict__ gateW, float* __restrict__ out)
{
  int idx = blockIdx.x*256 + threadIdx.x;   // float4 index
  int token = idx >> 6;
  int d4 = idx & 63;
  int b = token >> 11;
  float g1 = g1f[token], g2 = g2f[token];
  int e1 = idx1a[token], e2 = idx2a[token];
  float4 w1 = ((const float4*)(gateW + (size_t)(e1*BB+b)*DD))[d4];
  float4 w2 = ((const float4*)(gateW + (size_t)(e2*BB+b)*DD))[d4];
  float4 xv = ((const float4*)x)[idx];
  float4 o;
  o.x = xv.x*(g1*w1.x + g2*w2.x);
  o.y = xv.y*(g1*w1.y + g2*w2.y);
  o.z = xv.z*(g1*w1.z + g2*w2.z);
  o.w = xv.w*(g1*w1.w + g2*w2.w);
  ((float4*)out)[idx] = o;
}

// ================================================================ launcher
extern "C" void kernel_launch(void* const* d_in, const int* in_sizes, int n_in,
                              void* d_out, int out_size, void* d_ws, size_t ws_size,
                              hipStream_t stream)
{
  const float* x     = (const float*)d_in[0];
  const float* audio = (const float*)d_in[1];
  const float* wg    = (const float*)d_in[2];
  const float* Wq    = (const float*)d_in[3];
  const float* Wkv   = (const float*)d_in[4];
  const float* Wp    = (const float*)d_in[5];
  const float* bp    = (const float*)d_in[6];
  float* out = (float*)d_out;

  // workspace (~3.9 MB), no memsets needed
  float* raw_part = (float*)d_ws;                      // 256*16
  float* cnt_part = raw_part + 256*16;                 // 256*16
  int*   idx1a   = (int*)(cnt_part + 256*16);          // BN
  int*   idx2a   = idx1a + BN;                         // BN
  float* g1a     = (float*)(idx2a + BN);               // BN (scan truncates in place)
  float* g2a     = g1a + BN;                           // BN
  int*   slot_token = (int*)(g2a + BN);                // EB*CAP
  float* rws     = (float*)(slot_token + EB*CAPC);     // EB*2048
  float* dummy   = rws + (size_t)EB*2048;              // prefetch sink (>=1024 floats)
  float* gateW   = dummy + 1024;                       // EB*256

  fused_gq_kernel<<<384, 256, 0, stream>>>(x, wg, audio, Wq, Wkv,
                                           idx1a, idx2a, g1a, g2a,
                                           raw_part, cnt_part, rws);
  scan_kernel<<<64, 256, 0, stream>>>(idx1a, idx2a, g1a, g2a, slot_token,
                                      raw_part, cnt_part, Wkv, Wp, dummy,
                                      out + (size_t)out_size - 1);
  expert_kernel<<<EB, 512, 0, stream>>>(x, rws, slot_token, Wkv, Wp, bp, gateW);
  out_kernel<<<(BN*DD/4)/256, 256, 0, stream>>>(x, g1a, g2a, idx1a, idx2a, gateW, out);
}

// Round 2
// 140.406 us; speedup vs baseline: 1.1080x; 1.0918x over previous
//
#include <hip/hip_runtime.h>
#include <cstdint>
#include <cstddef>

#define BB 8
#define NN 2048
#define DD 256
#define EE 16
#define HH 8
#define CAPC 256
#define BN (BB*NN)   // 16384
#define EB (EE*BB)   // 128

// ================================================================ kernel 1:
// blocks 0..255   : gating (64 tokens each), per-block loss partials
// blocks 256..383 : qr per (e,h): q[b]=audio[b]@Wq[e]; r[b][d]=Wk[e][d,h*32:]·q_head
// blocks 384..447 : L3 prefetch of Wkv V-half + Wp (overlaps gating; the 256 MiB
//                   harness poison fills evict L3 every iteration, so the expert
//                   phase would otherwise read these cold on its critical path)
__global__ __launch_bounds__(256) void fused_gq_kernel(
    const float* __restrict__ x, const float* __restrict__ wg,
    const float* __restrict__ audio, const float* __restrict__ Wq,
    const float* __restrict__ Wkv, const float* __restrict__ Wp,
    int* __restrict__ idx1a, int* __restrict__ idx2a,
    float* __restrict__ g1a, float* __restrict__ g2a,
    float* __restrict__ raw_part, float* __restrict__ cnt_part,
    float* __restrict__ rws, float* __restrict__ dummy)
{
  __shared__ union SM {
    struct { float wgS[DD*EE]; float lgp[4][64][17]; } g;                     // 33.4 KB
    struct { float aS[DD][8]; float qpart[8][32][9]; float qS[32][8];
             float wkS[DD][33]; } q;                                          // 52 KB
  } sm;
  int tid = threadIdx.x;

  if (blockIdx.x >= 384) {
    // ---------------- L3 prefetch: Wkv V-half (262144 f4) + Wp (262144 f4) ----
    int pid = (blockIdx.x - 384)*256 + tid;      // 0..16383
    const float4* wk4 = (const float4*)Wkv;
    const float4* wp4 = (const float4*)Wp;
    float s = 0.f;
    for (int i = pid; i < 524288; i += 64*256) {
      float4 v;
      if (i < 262144) {
        int e = i >> 14, rem = i & 16383;        // 16384 f4 per expert V-half
        int row = rem >> 6, c4 = rem & 63;
        v = wk4[e*32768 + row*128 + 64 + c4];    // V = cols 256..511 of 512-wide row
      } else {
        v = wp4[i - 262144];
      }
      s += v.x + v.y + v.z + v.w;
    }
    if (s != 0.f) dummy[pid & 1023] = s;         // keep loads live
    return;
  }

  if (blockIdx.x < 256) {
    // ---------------- gating ----------------
    for (int t = tid; t < DD*EE; t += 256) sm.g.wgS[t] = wg[t];
    __syncthreads();
    int tk = tid & 63, kc = tid >> 6;
    int token0 = blockIdx.x * 64;
    int token = token0 + tk;
    const float4* xr = (const float4*)(x + (size_t)token*DD + kc*64);
    const float4* wg4 = (const float4*)sm.g.wgS;
    float lg[16];
#pragma unroll
    for (int e = 0; e < 16; ++e) lg[e] = 0.f;
#pragma unroll
    for (int d4 = 0; d4 < 16; ++d4) {
      float4 xv = xr[d4];
      float xa[4] = {xv.x, xv.y, xv.z, xv.w};
#pragma unroll
      for (int dd = 0; dd < 4; ++dd) {
        int d = kc*64 + d4*4 + dd;
        float xc = xa[dd];
#pragma unroll
        for (int j = 0; j < 4; ++j) {
          float4 w = wg4[d*4 + j];
          lg[4*j+0] += xc*w.x; lg[4*j+1] += xc*w.y;
          lg[4*j+2] += xc*w.z; lg[4*j+3] += xc*w.w;
        }
      }
    }
#pragma unroll
    for (int e = 0; e < 16; ++e) sm.g.lgp[kc][tk][e] = lg[e];
    __syncthreads();
    if (tid < 64) {
      int lane = tid;
      float l[16];
#pragma unroll
      for (int e = 0; e < 16; ++e)
        l[e] = sm.g.lgp[0][lane][e] + sm.g.lgp[1][lane][e]
             + sm.g.lgp[2][lane][e] + sm.g.lgp[3][lane][e];
      float mx = l[0];
#pragma unroll
      for (int e = 1; e < 16; ++e) mx = fmaxf(mx, l[e]);
      float p[16]; float s = 0.f;
#pragma unroll
      for (int e = 0; e < 16; ++e) { p[e] = expf(l[e] - mx); s += p[e]; }
      int i1 = 0; float b1 = p[0];
#pragma unroll
      for (int e = 1; e < 16; ++e) { if (p[e] > b1) { b1 = p[e]; i1 = e; } }
      float b2 = (i1 == 0) ? 0.f : p[0]; int i2 = 0;
#pragma unroll
      for (int e = 1; e < 16; ++e) { float v = (e == i1) ? 0.f : p[e]; if (v > b2) { b2 = v; i2 = e; } }
      float inv = 1.f / s;
      float g1 = b1*inv, g2 = b2*inv;
      float den = g1 + g2 + 1e-9f;
      g1 /= den; g2 /= den;
      int tok = token0 + lane;
      idx1a[tok] = i1; idx2a[tok] = i2;
      g1a[tok] = g1;   g2a[tok] = g2;
      int blk = blockIdx.x;
#pragma unroll
      for (int e = 0; e < 16; ++e) {
        float v = p[e] * inv;
        v += __shfl_down(v, 32); v += __shfl_down(v, 16);
        v += __shfl_down(v, 8);  v += __shfl_down(v, 4);
        v += __shfl_down(v, 2);  v += __shfl_down(v, 1);
        unsigned long long mb = __ballot(i1 == e);
        if (lane == 0) {
          raw_part[blk*16 + e] = v;
          cnt_part[blk*16 + e] = (float)__popcll(mb);
        }
      }
    }
  } else {
    // ---------------- qr per (e,h) ----------------
    int eh = blockIdx.x - 256;
    int e = eh >> 3, h = eh & 7;
    for (int i = tid; i < 2048; i += 256) { int b = i >> 8, k = i & 255; sm.q.aS[k][b] = audio[b*DD + k]; }
    __syncthreads();
    int j = tid & 31, kg = tid >> 5;
    const float* wq = Wq + (size_t)e*DD*DD + h*32 + j;
    float acc[8] = {0,0,0,0,0,0,0,0};
#pragma unroll
    for (int i = 0; i < 32; ++i) {
      int k = kg*32 + i;
      float w = wq[(size_t)k*DD];
      float4 a0 = *(const float4*)&sm.q.aS[k][0];
      float4 a1 = *(const float4*)&sm.q.aS[k][4];
      acc[0]+=w*a0.x; acc[1]+=w*a0.y; acc[2]+=w*a0.z; acc[3]+=w*a0.w;
      acc[4]+=w*a1.x; acc[5]+=w*a1.y; acc[6]+=w*a1.z; acc[7]+=w*a1.w;
    }
#pragma unroll
    for (int b = 0; b < 8; ++b) sm.q.qpart[kg][j][b] = acc[b];
    const float* wkbase = Wkv + (size_t)e*(DD*2*DD) + h*32;
    float4 stg[8];
#pragma unroll
    for (int m = 0; m < 8; ++m) {
      int row = m*32 + (tid >> 3), c4 = tid & 7;
      stg[m] = *(const float4*)(wkbase + (size_t)row*(2*DD) + c4*4);
    }
#pragma unroll
    for (int m = 0; m < 8; ++m) {
      int row = m*32 + (tid >> 3), c4 = tid & 7;
      sm.q.wkS[row][c4*4+0] = stg[m].x; sm.q.wkS[row][c4*4+1] = stg[m].y;
      sm.q.wkS[row][c4*4+2] = stg[m].z; sm.q.wkS[row][c4*4+3] = stg[m].w;
    }
    __syncthreads();
    {
      int jj = tid >> 3, b = tid & 7;
      float s = 0.f;
#pragma unroll
      for (int g = 0; g < 8; ++g) s += sm.q.qpart[g][jj][b];
      sm.q.qS[jj][b] = s;
    }
    __syncthreads();
    int d = tid;
    float racc[8] = {0,0,0,0,0,0,0,0};
#pragma unroll
    for (int jj = 0; jj < 32; ++jj) {
      float w = sm.q.wkS[d][jj];
      float4 q0 = *(const float4*)&sm.q.qS[jj][0];
      float4 q1 = *(const float4*)&sm.q.qS[jj][4];
      racc[0]+=w*q0.x; racc[1]+=w*q0.y; racc[2]+=w*q0.z; racc[3]+=w*q0.w;
      racc[4]+=w*q1.x; racc[5]+=w*q1.y; racc[6]+=w*q1.z; racc[7]+=w*q1.w;
    }
#pragma unroll
    for (int b = 0; b < 8; ++b)
      rws[((size_t)(e*8 + b))*2048 + d*8 + h] = racc[b];
  }
}

// ================================================================ kernel 2 (fused):
// per (e,b) block: in-LDS capacity scan (only i==e ballots) -> slot logits ->
// softmax -> attn gather -> @Wv -> @Wp + sigmoid.  grid = EB x 512 threads.
__global__ __launch_bounds__(512) void expert_kernel(
    const float* __restrict__ x, const float* __restrict__ rws,
    const int* __restrict__ idx1a, const int* __restrict__ idx2a,
    float* __restrict__ g1a, float* __restrict__ g2a,
    const float* __restrict__ Wkv,
    const float* __restrict__ Wp, const float* __restrict__ bp,
    float* __restrict__ gateW)
{
  __shared__ float rS[DD][8];        // 8 KB   r[d][h]
  __shared__ int   tokS[CAPC];       // 1 KB
  __shared__ float lp[2][CAPC][9];   // 18.4 KB logit partials
  __shared__ float aST[CAPC][8];     // 8 KB   logits, then probs [s][h]
  __shared__ float part[2][8][DD];   // 16 KB  gather partials
  __shared__ float xaS[8][DD];       // 8 KB   attn-weighted x [h][d]
  __shared__ float oS[DD];           // 1 KB
  __shared__ float op[2][DD];        // 2 KB
  __shared__ unsigned long long s_m1[32], s_m2[32];   // per-chunk ballots (this e)
  __shared__ int s_wp1[32], s_wp2[32], s_m1cnt;
  int tid = threadIdx.x;
  int eb = blockIdx.x;
  int e  = eb >> 3;
  int b  = eb & 7;

  // ---- rS load + slot-list scan (batch b, expert e only) ----
  {
    const float4* rin = (const float4*)(rws + (size_t)eb*2048);
    ((float4*)rS)[tid] = rin[tid];                // 512 f4 = 8 KB
    if (tid < CAPC) tokS[tid] = -1;
  }
  int wave = tid >> 6, lane = tid & 63;
  {
#pragma unroll
    for (int cc = 0; cc < 4; ++cc) {
      int c = wave*4 + cc;                        // chunk 0..31 (64 tokens each)
      int token = b*NN + c*64 + lane;
      int i1 = idx1a[token], i2 = idx2a[token];
      unsigned long long ma = __ballot(i1 == e);
      unsigned long long mb = __ballot(i2 == e);
      if (lane == 0) { s_m1[c] = ma; s_m2[c] = mb; }
    }
  }
  __syncthreads();
  if (tid == 0) {
    int run = 0;
    for (int c = 0; c < 32; ++c) { s_wp1[c] = run; run += (int)__popcll(s_m1[c]); }
    s_m1cnt = run < CAPC ? run : CAPC;
  } else if (tid == 64) {
    int run = 0;
    for (int c = 0; c < 32; ++c) { s_wp2[c] = run; run += (int)__popcll(s_m2[c]); }
  }
  __syncthreads();
  {
    int m1cnt = s_m1cnt;
#pragma unroll
    for (int cc = 0; cc < 4; ++cc) {
      int c = wave*4 + cc;
      int token = b*NN + c*64 + lane;
      int i1 = idx1a[token], i2 = idx2a[token];
      unsigned long long lt = (1ull << lane) - 1ull;
      if (i1 == e) {
        int pos1 = s_wp1[c] + (int)__popcll(s_m1[c] & lt);
        if (pos1 < CAPC) tokS[pos1] = token;
        else g1a[token] = 0.f;
      }
      if (i2 == e) {
        int pos2 = m1cnt + s_wp2[c] + (int)__popcll(s_m2[c] & lt);
        if (pos2 < CAPC) {
          if (g2a[token] > 0.f) tokS[pos2] = token;
        } else g2a[token] = 0.f;
      }
    }
  }
  __syncthreads();

  // ---- phase A: logits  l[s][h] = sum_d x[tok_s][d] * r[d][h] ----
  {
    int s = tid >> 1, q = tid & 1;     // 2 threads per slot, interleaved f4
    int token = tokS[s];
    float l[8] = {0,0,0,0,0,0,0,0};
    if (token >= 0) {
      const float4* xr = (const float4*)(x + (size_t)token*DD) + q;
#pragma unroll
      for (int i = 0; i < 32; ++i) {
        float4 xv = xr[i*2];
        float xa[4] = {xv.x, xv.y, xv.z, xv.w};
#pragma unroll
        for (int dd = 0; dd < 4; ++dd) {
          int d = i*8 + q*4 + dd;
          float4 r0 = *(const float4*)&rS[d][0];
          float4 r1 = *(const float4*)&rS[d][4];
          float xc = xa[dd];
          l[0]+=xc*r0.x; l[1]+=xc*r0.y; l[2]+=xc*r0.z; l[3]+=xc*r0.w;
          l[4]+=xc*r1.x; l[5]+=xc*r1.y; l[6]+=xc*r1.z; l[7]+=xc*r1.w;
        }
      }
    }
#pragma unroll
    for (int h = 0; h < 8; ++h) lp[q][s][h] = l[h];
  }
  __syncthreads();
#pragma unroll
  for (int r = 0; r < 4; ++r) {
    int idx = r*512 + tid;             // 0..2047
    int s2 = idx >> 3, h2 = idx & 7;
    aST[s2][h2] = (lp[0][s2][h2] + lp[1][s2][h2]) * 0.17677669529663687f; // 32^-0.5
  }
  __syncthreads();

  // ---- phase B: softmax over 256 slots per head (wave w owns head h=w) ----
  {
    int h = wave;
    float v0 = aST[lane][h],     v1 = aST[lane+64][h];
    float v2 = aST[lane+128][h], v3 = aST[lane+192][h];
    float m = fmaxf(fmaxf(v0, v1), fmaxf(v2, v3));
    m = fmaxf(m, __shfl_down(m, 32)); m = fmaxf(m, __shfl_down(m, 16));
    m = fmaxf(m, __shfl_down(m, 8));  m = fmaxf(m, __shfl_down(m, 4));
    m = fmaxf(m, __shfl_down(m, 2));  m = fmaxf(m, __shfl_down(m, 1));
    m = __shfl(m, 0);
    float e0 = expf(v0 - m), e1 = expf(v1 - m), e2 = expf(v2 - m), e3 = expf(v3 - m);
    float sm = e0 + e1 + e2 + e3;
    sm += __shfl_down(sm, 32); sm += __shfl_down(sm, 16); sm += __shfl_down(sm, 8);
    sm += __shfl_down(sm, 4);  sm += __shfl_down(sm, 2);  sm += __shfl_down(sm, 1);
    sm = __shfl(sm, 0);
    float inv = 1.f / sm;
    aST[lane][h]     = e0*inv; aST[lane+64][h]  = e1*inv;
    aST[lane+128][h] = e2*inv; aST[lane+192][h] = e3*inv;
  }
  __syncthreads();

  // ---- phase C: gather  xa[h][d] = sum_s a[s][h] * x[tok_s][d] ----
  {
    int d = tid & 255, sc = tid >> 8;  // sc in {0,1}: 128 slots each
    const float* xb = x + d;
    float acc[8] = {0,0,0,0,0,0,0,0};
#pragma unroll 4
    for (int i = 0; i < 128; ++i) {
      int s2 = sc*128 + i;
      int tk = tokS[s2];
      int tkc = tk < 0 ? 0 : tk;
      float msk = tk < 0 ? 0.f : 1.f;
      float xv = xb[(size_t)tkc*DD] * msk;
      float4 a0 = *(const float4*)&aST[s2][0];
      float4 a1 = *(const float4*)&aST[s2][4];
      acc[0]+=a0.x*xv; acc[1]+=a0.y*xv; acc[2]+=a0.z*xv; acc[3]+=a0.w*xv;
      acc[4]+=a1.x*xv; acc[5]+=a1.y*xv; acc[6]+=a1.z*xv; acc[7]+=a1.w*xv;
    }
#pragma unroll
    for (int h = 0; h < 8; ++h) part[sc][h][d] = acc[h];
  }
  __syncthreads();
#pragma unroll
  for (int r = 0; r < 4; ++r) {
    int idx = r*512 + tid;
    int h2 = idx >> 8, d2 = idx & 255;
    xaS[h2][d2] = part[0][h2][d2] + part[1][h2][d2];
  }
  __syncthreads();

  // ---- phase D: o[c] = sum_d xa[h(c)][d] * Wv[d][c],  h(c)=c>>5 ----
  {
    int c = tid & 255, kc = tid >> 8;
    int h = c >> 5;
    const float* wv = Wkv + (size_t)e*(DD*2*DD) + DD + c;
    float a = 0.f;
#pragma unroll 8
    for (int i = 0; i < 128; ++i) {
      int d2 = kc*128 + i;
      a += wv[(size_t)d2*(2*DD)] * xaS[h][d2];
    }
    op[kc][c] = a;
  }
  __syncthreads();
  if (tid < DD) oS[tid] = op[0][tid] + op[1][tid];
  __syncthreads();

  // ---- phase E: gate[c] = sigmoid(bp[c] + sum_d o[d] * Wp[d][c]) ----
  {
    int c = tid & 255, kc = tid >> 8;
    const float* wp = Wp + (size_t)e*DD*DD + c;
    float a = 0.f;
#pragma unroll 8
    for (int i = 0; i < 128; ++i) {
      int d2 = kc*128 + i;
      a += wp[(size_t)d2*DD] * oS[d2];
    }
    op[kc][c] = a;
  }
  __syncthreads();
  if (tid < DD) {
    float sv = bp[e*DD + tid] + op[0][tid] + op[1][tid];
    gateW[(size_t)eb*DD + tid] = 1.f / (1.f + expf(-sv));
  }
}

// ================================================================ kernel 3: recombine (float4) + loss in last block
__global__ __launch_bounds__(256) void out_kernel(
    const float* __restrict__ x, const float* __restrict__ g1f, const float* __restrict__ g2f,
    const int* __restrict__ idx1a, const int* __restrict__ idx2a,
    const float* __restrict__ gateW,
    const float* __restrict__ raw_part, const float* __restrict__ cnt_part,
    float* __restrict__ out, float* __restrict__ out_loss)
{
  int idx = blockIdx.x*256 + threadIdx.x;   // float4 index
  int token = idx >> 6;
  int d4 = idx & 63;
  int b = token >> 11;
  float g1 = g1f[token], g2 = g2f[token];
  int e1 = idx1a[token], e2 = idx2a[token];
  float4 w1 = ((const float4*)(gateW + (size_t)(e1*BB+b)*DD))[d4];
  float4 w2 = ((const float4*)(gateW + (size_t)(e2*BB+b)*DD))[d4];
  float4 xv = ((const float4*)x)[idx];
  float4 o;
  o.x = xv.x*(g1*w1.x + g2*w2.x);
  o.y = xv.y*(g1*w1.y + g2*w2.y);
  o.z = xv.z*(g1*w1.z + g2*w2.z);
  o.w = xv.w*(g1*w1.w + g2*w2.w);
  ((float4*)out)[idx] = o;

  if (blockIdx.x == gridDim.x - 1) {
    int tid = threadIdx.x;
    float v = 0.f;
    if (tid < 128) {
      int bb = tid >> 4, e = tid & 15;
      float rs = 0.f, cs = 0.f;
#pragma unroll 4
      for (int k = 0; k < 32; ++k) {
        rs += raw_part[(bb*32 + k)*16 + e];
        cs += cnt_part[(bb*32 + k)*16 + e];
      }
      v = (rs * (1.f/(float)NN)) * (cs * (1.f/(float)NN));
    }
    v += __shfl_down(v, 32); v += __shfl_down(v, 16); v += __shfl_down(v, 8);
    v += __shfl_down(v, 4);  v += __shfl_down(v, 2);  v += __shfl_down(v, 1);
    __shared__ float r4[4];
    if ((tid & 63) == 0) r4[tid >> 6] = v;
    __syncthreads();
    if (tid == 0)
      out_loss[0] = (r4[0]+r4[1]+r4[2]+r4[3]) * ((float)(EE*EE) / (float)(BB*EE)) * 0.01f;
  }
}

// ================================================================ launcher
extern "C" void kernel_launch(void* const* d_in, const int* in_sizes, int n_in,
                              void* d_out, int out_size, void* d_ws, size_t ws_size,
                              hipStream_t stream)
{
  const float* x     = (const float*)d_in[0];
  const float* audio = (const float*)d_in[1];
  const float* wg    = (const float*)d_in[2];
  const float* Wq    = (const float*)d_in[3];
  const float* Wkv   = (const float*)d_in[4];
  const float* Wp    = (const float*)d_in[5];
  const float* bp    = (const float*)d_in[6];
  float* out = (float*)d_out;

  // workspace (~3.5 MB), no memsets needed
  float* raw_part = (float*)d_ws;                      // 256*16
  float* cnt_part = raw_part + 256*16;                 // 256*16
  int*   idx1a   = (int*)(cnt_part + 256*16);          // BN
  int*   idx2a   = idx1a + BN;                         // BN
  float* g1a     = (float*)(idx2a + BN);               // BN (expert truncates in place)
  float* g2a     = g1a + BN;                           // BN
  float* rws     = g2a + BN;                           // EB*2048
  float* dummy   = rws + (size_t)EB*2048;              // prefetch sink (>=1024 floats)
  float* gateW   = dummy + 1024;                       // EB*256

  fused_gq_kernel<<<448, 256, 0, stream>>>(x, wg, audio, Wq, Wkv, Wp,
                                           idx1a, idx2a, g1a, g2a,
                                           raw_part, cnt_part, rws, dummy);
  expert_kernel<<<EB, 512, 0, stream>>>(x, rws, idx1a, idx2a, g1a, g2a,
                                        Wkv, Wp, bp, gateW);
  out_kernel<<<(BN*DD/4)/256, 256, 0, stream>>>(x, g1a, g2a, idx1a, idx2a, gateW,
                                                raw_part, cnt_part,
                                                out, out + (size_t)out_size - 1);
}